// Round 4
// baseline (833.283 us; speedup 1.0000x reference)
//
#include <hip/hip_runtime.h>
#include <hip/hip_bf16.h>

// Problem constants
#define B_    512
#define HIST_ 8
#define PRED_ 24
#define CITY_ 184
#define FEAT_ 13
#define HID_  32
#define BC_   (B_*CITY_)   // 94208 = 5888 * 16
#define FLAG_OFF 7168

// ws (float) layout (written by lstm_prep):
//   [0..4095]      Wh2[row*32+k] : W_hh + a0 (x) W_out   (t>=1 path)
//   [4096..6143]   Wf [row*16+f] : W_x[:,1:14], cols 13..15 zeroed
//   [6144..6271]   bg2[row]      : b_g + a0*b_out        (t>=1)
//   [6272..6399]   a0 [row]      : W_x[:,0]              (t==0)
//   [6400..6527]   bg0[row]      : b_g                   (t==0)
//   [6528..6559]   wout[k]
//   [6560]         bout
//   [7168]         dtype flag: 0.0f = bf16 inputs, 1.0f = fp32 inputs

typedef float v2f __attribute__((ext_vector_type(2)));

struct TrueT  { static constexpr bool value = true;  };
struct FalseT { static constexpr bool value = false; };

__device__ __forceinline__ float rcp_(float x) { return __builtin_amdgcn_rcpf(x); }
__device__ __forceinline__ float sigf(float x) { return rcp_(1.0f + __expf(-x)); }
__device__ __forceinline__ float tanhf_(float x) {
    float e = __expf(2.0f * x);
    return 1.0f - 2.0f * rcp_(e + 1.0f);   // saturates correctly
}
__device__ __forceinline__ v2f fma2(v2f a, v2f b, v2f c) {
    return __builtin_elementwise_fma(a, b, c);
}

template<bool F32>
__device__ __forceinline__ float ldin(const void* p, long i) {
    if constexpr (F32) return ((const float*)p)[i];
    else               return __bfloat162float(((const __hip_bfloat16*)p)[i]);
}
template<bool F32>
__device__ __forceinline__ void stout(void* p, long i, float v) {
    if constexpr (F32) ((float*)p)[i] = v;
    else               ((__hip_bfloat16*)p)[i] = __float2bfloat16(v);
}

// ---- dtype detector (validated in R2/R3) ----
__global__ void detect_dtype(const unsigned short* __restrict__ feat_raw,
                             float* __restrict__ ws) {
    __shared__ int cnt;
    int tid = threadIdx.x;
    if (tid == 0) cnt = 0;
    __syncthreads();
    int insane = 0;
    for (int i = tid; i < 4096; i += 256) {
        float v = __uint_as_float(((unsigned int)feat_raw[i]) << 16);
        if (!(fabsf(v) < 1e8f)) insane++;
    }
    if (insane) atomicAdd(&cnt, insane);
    __syncthreads();
    if (tid == 0) ws[FLAG_OFF] = (cnt > 8) ? 1.0f : 0.0f;
}

template<bool F32>
__global__ void lstm_prep(const void* __restrict__ W_in,   // (32,14)
                          const void* __restrict__ b_in,   // (32)
                          const void* __restrict__ W_out,  // (1,32)
                          const void* __restrict__ b_out,  // (1)
                          const void* __restrict__ W_ih,   // (128,32)
                          const void* __restrict__ W_hh,   // (128,32)
                          const void* __restrict__ b_ih,   // (128)
                          const void* __restrict__ b_hh,   // (128)
                          float* __restrict__ ws)
{
    if (ws[FLAG_OFF] != (F32 ? 1.0f : 0.0f)) return;
    int j = threadIdx.x;           // gate row 0..127
    if (j >= 128) return;

    float wx[14];
    #pragma unroll
    for (int c = 0; c < 14; ++c) wx[c] = 0.0f;
    float bg = ldin<F32>(b_ih, j) + ldin<F32>(b_hh, j);
    #pragma unroll
    for (int m = 0; m < 32; ++m) {
        float wihm = ldin<F32>(W_ih, j*32 + m);
        #pragma unroll
        for (int c = 0; c < 14; ++c) wx[c] = fmaf(wihm, ldin<F32>(W_in, m*14 + c), wx[c]);
        bg = fmaf(wihm, ldin<F32>(b_in, m), bg);
    }
    float a0 = wx[0];
    #pragma unroll
    for (int k = 0; k < 32; ++k)
        ws[j*32 + k] = ldin<F32>(W_hh, j*32 + k) + a0 * ldin<F32>(W_out, k);
    #pragma unroll
    for (int f = 0; f < 13; ++f) ws[4096 + j*16 + f] = wx[1 + f];
    #pragma unroll
    for (int f = 13; f < 16; ++f) ws[4096 + j*16 + f] = 0.0f;
    float bo = ldin<F32>(b_out, 0);
    ws[6144 + j] = bg + a0 * bo;
    ws[6272 + j] = a0;
    ws[6400 + j] = bg;
    if (j < 32) ws[6528 + j] = ldin<F32>(W_out, j);
    if (j == 0) ws[6560] = bo;
}

// Gate-split weight-stationary LSTM. 1 wave/block, 16 seqs/wave.
// half0 (lanes 0..31): gate rows u (i) and u+32 (f) of unit u=lane&31.
// half1 (lanes 32..63): gate rows u+64 (g) and u+96 (o).
// Round r processes sequence wseq+r: ~90 weight floats/lane stay in VGPRs.
template<bool F32>
__global__ __launch_bounds__(64) __attribute__((amdgpu_waves_per_eu(2, 3)))
void lstm_main(
    const void* __restrict__ pm25,   // (512, 8, 184, 1)
    const void* __restrict__ feat,   // (512, 32, 184, 13)
    const float* __restrict__ ws,
    void* __restrict__ out)          // (512, 24, 184, 1)
{
    __shared__ float hb[16][36];     // row-broadcast reads; 8B-aligned rows for v2f
    __shared__ float fb[16][16];
    if (ws[FLAG_OFF] != (F32 ? 1.0f : 0.0f)) return;

    const int lane = threadIdx.x;    // 0..63
    const int u    = lane & 31;
    const int half = lane >> 5;
    const int wseq = blockIdx.x * 16;

    // ---- resident weights: 2 gate rows per lane ----
    const int row0 = u + 64*half;    // i (half0) / g (half1)
    const int row1 = row0 + 32;      // f (half0) / o (half1)
    v2f Wh0[16], Wh1[16];
    {
        const v2f* w0 = (const v2f*)(ws + row0*32);
        const v2f* w1 = (const v2f*)(ws + row1*32);
        #pragma unroll
        for (int q = 0; q < 16; ++q) { Wh0[q] = w0[q]; Wh1[q] = w1[q]; }
    }
    v2f Wf0[6], Wf1[6];
    {
        const v2f* w0 = (const v2f*)(ws + 4096 + row0*16);
        const v2f* w1 = (const v2f*)(ws + 4096 + row1*16);
        #pragma unroll
        for (int q = 0; q < 6; ++q) { Wf0[q] = w0[q]; Wf1[q] = w1[q]; }
    }
    const float w12r0 = ws[4096 + row0*16 + 12];
    const float w12r1 = ws[4096 + row1*16 + 12];
    const float bg2r0 = ws[6144 + row0], bg2r1 = ws[6144 + row1];
    const float a0r0  = ws[6272 + row0], a0r1  = ws[6272 + row1];
    const float bg0r0 = ws[6400 + row0], bg0r1 = ws[6400 + row1];
    const float wo = ws[6528 + u];
    const float bo = ws[6560];

    // ---- per-lane seq meta (lane&15 -> seq wseq+(lane&15)) ----
    int obase; float x0reg;
    {
        const int msl  = lane & 15;
        const int mseq = wseq + msl;
        const int mb   = mseq / CITY_;
        const int mc   = mseq - mb*CITY_;
        obase = mb*(PRED_*CITY_) + mc;
        x0reg = ldin<F32>(pm25, (long)(mb*HIST_ + (HIST_-1))*CITY_ + mc);
    }

    // ---- feature staging: 16 seqs x 13 feats = 208 elems; lanes x 4 slots ----
    int fofs[4], fsl[4], fff[4];
    #pragma unroll
    for (int j = 0; j < 4; ++j) {
        int e = lane + 64*j;
        if (j == 3 && lane >= 16) e = lane;       // dummy (never written)
        const int sl = e / FEAT_;
        const int f  = e - sl*FEAT_;
        fsl[j] = sl; fff[j] = f;
        const int seq  = wseq + sl;
        const int b    = seq / CITY_;
        const int city = seq - b*CITY_;
        fofs[j] = ((b*(HIST_+PRED_) + HIST_)*CITY_ + city)*FEAT_ + f;
    }
    float fval[4];
    auto ldfeat = [&]() {
        #pragma unroll
        for (int j = 0; j < 4; ++j) {
            fval[j] = ldin<F32>(feat, (long)fofs[j]);
            fofs[j] += CITY_ * FEAT_;
        }
    };
    auto wrfeat = [&]() {
        #pragma unroll
        for (int j = 0; j < 3; ++j) fb[fsl[j]][fff[j]] = fval[j];
        if (lane < 16) fb[fsl[3]][fff[3]] = fval[3];
    };

    float cst[16];                   // c-state (valid on half0 lanes)

    auto round_body = [&](int t, int r, auto T0flag) {
        constexpr bool T0 = decltype(T0flag)::value;
        const int sl = r;
        v2f A0, A1;
        if constexpr (T0) {
            const float x0 = __shfl(x0reg, sl);         // readlane (const)
            A0 = v2f{fmaf(a0r0, x0, bg0r0), 0.0f};
            A1 = v2f{fmaf(a0r1, x0, bg0r1), 0.0f};
        } else {
            A0 = v2f{bg2r0, 0.0f};
            A1 = v2f{bg2r1, 0.0f};
            const v2f* hp = (const v2f*)(&hb[sl][0]);   // broadcast reads
            #pragma unroll
            for (int q = 0; q < 16; ++q) {
                const v2f h2 = hp[q];
                A0 = fma2(Wh0[q], h2, A0);
                A1 = fma2(Wh1[q], h2, A1);
            }
        }
        {
            const v2f* fp = (const v2f*)(&fb[sl][0]);
            #pragma unroll
            for (int q = 0; q < 6; ++q) {
                const v2f f2v = fp[q];
                A0 = fma2(Wf0[q], f2v, A0);
                A1 = fma2(Wf1[q], f2v, A1);
            }
        }
        const float f12 = fb[sl][12];
        const float acc0 = fmaf(w12r0, f12, A0.x + A0.y);
        const float acc1 = fmaf(w12r1, f12, A1.x + A1.y);

        // unified activations: half0 gate0 = sig(I); half1 gate0 = tanh(G)=2*sig(2G)-1
        const float s0   = sigf(half ? 2.0f*acc0 : acc0);
        const float val0 = half ? fmaf(2.0f, s0, -1.0f) : s0;   // I / G
        const float g1   = sigf(acc1);                          // F / O

        const float xG = __shfl_xor(val0, 32);   // half0 receives G
        const float prod = val0 * xG;            // half0: I*G
        const float cc = T0 ? prod : fmaf(g1, cst[r], prod);
        cst[r] = cc;
        const float th = tanhf_(cc);
        const float xO = __shfl_xor(g1, 32);     // half0 receives O
        const float hu = xO * th;                // half0: new h_u

        if (lane < 32) hb[sl][u] = hu;

        float y = wo * hu;                       // reduce over half0 lanes
        y += __shfl_xor(y, 1);
        y += __shfl_xor(y, 2);
        y += __shfl_xor(y, 4);
        y += __shfl_xor(y, 8);
        y += __shfl_xor(y, 16);
        const int ob = __shfl(obase, sl);        // readlane (const) -> SGPR
        if (lane == 0)
            stout<F32>(out, (long)(ob + t*CITY_), y + bo);
    };

    // ---- t = 0 ----
    ldfeat();            // t=0 features
    wrfeat();
    ldfeat();            // t=1 features in flight
    #pragma unroll
    for (int r = 0; r < 16; ++r) round_body(0, r, TrueT{});

    // ---- t = 1..23 ----
    #pragma unroll 1
    for (int t = 1; t < PRED_; ++t) {
        wrfeat();                       // features for t (loaded last iter)
        if (t < PRED_-1) ldfeat();      // prefetch t+1
        #pragma unroll
        for (int r = 0; r < 16; ++r) round_body(t, r, FalseT{});
    }
}

extern "C" void kernel_launch(void* const* d_in, const int* in_sizes, int n_in,
                              void* d_out, int out_size, void* d_ws, size_t ws_size,
                              hipStream_t stream) {
    const void* pm25  = d_in[0];
    const void* feat  = d_in[1];
    const void* W_in  = d_in[2];
    const void* b_in  = d_in[3];
    const void* W_out = d_in[4];
    const void* b_out = d_in[5];
    const void* W_ih  = d_in[6];
    const void* W_hh  = d_in[7];
    const void* b_ih  = d_in[8];
    const void* b_hh  = d_in[9];
    float* ws = (float*)d_ws;

    detect_dtype<<<dim3(1), dim3(256), 0, stream>>>((const unsigned short*)feat, ws);

    lstm_prep<false><<<dim3(1), dim3(128), 0, stream>>>(
        W_in, b_in, W_out, b_out, W_ih, W_hh, b_ih, b_hh, ws);
    lstm_prep<true><<<dim3(1), dim3(128), 0, stream>>>(
        W_in, b_in, W_out, b_out, W_ih, W_hh, b_ih, b_hh, ws);

    lstm_main<false><<<dim3(BC_/16), dim3(64), 0, stream>>>(pm25, feat, ws, d_out);
    lstm_main<true ><<<dim3(BC_/16), dim3(64), 0, stream>>>(pm25, feat, ws, d_out);
}

// Round 5
// 737.981 us; speedup vs baseline: 1.1291x; 1.1291x over previous
//
#include <hip/hip_runtime.h>
#include <hip/hip_bf16.h>

// Problem constants
#define B_    512
#define HIST_ 8
#define PRED_ 24
#define CITY_ 184
#define FEAT_ 13
#define HID_  32
#define BC_   (B_*CITY_)   // 94208 = 11776 waves * 8 seqs
#define FLAG_OFF 7168

// ws (float) layout (written by prep_all):
//   [0..4095]      Wh2[row*32+k] : W_hh + a0 (x) W_out   (t>=1 path)
//   [4096..6143]   Wf [row*16+f] : W_x[:,1:14], cols 13..15 zeroed
//   [6144..6271]   bg2[row]      : b_g + a0*b_out        (t>=1)
//   [6272..6399]   a0 [row]      : W_x[:,0]              (t==0)
//   [6400..6527]   bg0[row]      : b_g                   (t==0)
//   [6528..6559]   wout[k]
//   [6560]         bout
//   [7168]         dtype flag: 0.0f = bf16 inputs, 1.0f = fp32 inputs

// Anti-remat pin: value becomes opaque to the RA -> must stay in a VGPR.
#define PIN(x) asm volatile("" : "+v"(x))

struct TrueT  { static constexpr bool value = true;  };
struct FalseT { static constexpr bool value = false; };

__device__ __forceinline__ float rcp_(float x) { return __builtin_amdgcn_rcpf(x); }
__device__ __forceinline__ float sigf(float x) { return rcp_(1.0f + __expf(-x)); }
__device__ __forceinline__ float tanhf_(float x) {
    float e = __expf(2.0f * x);
    return 1.0f - 2.0f * rcp_(e + 1.0f);   // saturates correctly
}

template<bool F32>
__device__ __forceinline__ float ldin(const void* p, long i) {
    if constexpr (F32) return ((const float*)p)[i];
    else               return __bfloat162float(((const __hip_bfloat16*)p)[i]);
}
template<bool F32>
__device__ __forceinline__ void stout(void* p, long i, float v) {
    if constexpr (F32) ((float*)p)[i] = v;
    else               ((__hip_bfloat16*)p)[i] = __float2bfloat16(v);
}

// ---- weight folding (validated R2-R4) ----
template<bool F32>
__device__ __forceinline__ void prep_body(
    const void* __restrict__ W_in,  const void* __restrict__ b_in,
    const void* __restrict__ W_out, const void* __restrict__ b_out,
    const void* __restrict__ W_ih,  const void* __restrict__ W_hh,
    const void* __restrict__ b_ih,  const void* __restrict__ b_hh,
    float* __restrict__ ws, int j)
{
    float wx[14];
    #pragma unroll
    for (int c = 0; c < 14; ++c) wx[c] = 0.0f;
    float bg = ldin<F32>(b_ih, j) + ldin<F32>(b_hh, j);
    #pragma unroll
    for (int m = 0; m < 32; ++m) {
        float wihm = ldin<F32>(W_ih, j*32 + m);
        #pragma unroll
        for (int c = 0; c < 14; ++c) wx[c] = fmaf(wihm, ldin<F32>(W_in, m*14 + c), wx[c]);
        bg = fmaf(wihm, ldin<F32>(b_in, m), bg);
    }
    float a0 = wx[0];
    #pragma unroll
    for (int k = 0; k < 32; ++k)
        ws[j*32 + k] = ldin<F32>(W_hh, j*32 + k) + a0 * ldin<F32>(W_out, k);
    #pragma unroll
    for (int f = 0; f < 13; ++f) ws[4096 + j*16 + f] = wx[1 + f];
    #pragma unroll
    for (int f = 13; f < 16; ++f) ws[4096 + j*16 + f] = 0.0f;
    float bo = ldin<F32>(b_out, 0);
    ws[6144 + j] = bg + a0 * bo;
    ws[6272 + j] = a0;
    ws[6400 + j] = bg;
    if (j < 32) ws[6528 + j] = ldin<F32>(W_out, j);
    if (j == 0) ws[6560] = bo;
}

// Single dispatch: dtype detect (validated R2-R4) + fold, branch on result.
__global__ void prep_all(const unsigned short* __restrict__ feat_raw,
                         const void* __restrict__ W_in,  const void* __restrict__ b_in,
                         const void* __restrict__ W_out, const void* __restrict__ b_out,
                         const void* __restrict__ W_ih,  const void* __restrict__ W_hh,
                         const void* __restrict__ b_ih,  const void* __restrict__ b_hh,
                         float* __restrict__ ws)
{
    __shared__ int cnt;
    const int tid = threadIdx.x;     // 128 threads
    if (tid == 0) cnt = 0;
    __syncthreads();
    int insane = 0;
    for (int i = tid; i < 4096; i += 128) {
        float v = __uint_as_float(((unsigned int)feat_raw[i]) << 16);
        if (!(fabsf(v) < 1e8f)) insane++;   // catches NaN too
    }
    if (insane) atomicAdd(&cnt, insane);
    __syncthreads();
    const bool f32 = (cnt > 8);
    if (tid == 0) ws[FLAG_OFF] = f32 ? 1.0f : 0.0f;
    if (f32) prep_body<true >(W_in,b_in,W_out,b_out,W_ih,W_hh,b_ih,b_hh,ws,tid);
    else     prep_body<false>(W_in,b_in,W_out,b_out,W_ih,W_hh,b_ih,b_hh,ws,tid);
}

// Gate-split weight-stationary LSTM body. One wave, 8 sequences.
// half0 (lanes 0..31): gate rows u (i) and u+32 (f); half1: u+64 (g), u+96 (o).
template<bool F32>
__device__ __forceinline__ void lstm_body(
    const void* __restrict__ pm25, const void* __restrict__ feat,
    const float* __restrict__ ws, void* __restrict__ out,
    float (&hb)[8][36], float (&fb)[8][16], const int lane, const int wseq)
{
    const int u    = lane & 31;
    const int half = lane >> 5;
    const int row0 = u + 64*half;    // i / g
    const int row1 = row0 + 32;      // f / o

    // ---- resident weights, pinned against remat ----
    float Wh0[32], Wh1[32], Wf0[13], Wf1[13];
    {
        const float* p0 = ws + row0*32;
        const float* p1 = ws + row1*32;
        #pragma unroll
        for (int k = 0; k < 32; ++k) { Wh0[k] = p0[k]; Wh1[k] = p1[k]; }
        const float* q0 = ws + 4096 + row0*16;
        const float* q1 = ws + 4096 + row1*16;
        #pragma unroll
        for (int f = 0; f < 13; ++f) { Wf0[f] = q0[f]; Wf1[f] = q1[f]; }
    }
    float bg2r0 = ws[6144 + row0], bg2r1 = ws[6144 + row1];
    float a0r0  = ws[6272 + row0], a0r1  = ws[6272 + row1];
    float bg0r0 = ws[6400 + row0], bg0r1 = ws[6400 + row1];
    float wo    = ws[6528 + u];
    const float bo = ws[6560];
    #pragma unroll
    for (int k = 0; k < 32; ++k) { PIN(Wh0[k]); PIN(Wh1[k]); }
    #pragma unroll
    for (int f = 0; f < 13; ++f) { PIN(Wf0[f]); PIN(Wf1[f]); }
    PIN(bg2r0); PIN(bg2r1); PIN(a0r0); PIN(a0r1);
    PIN(bg0r0); PIN(bg0r1); PIN(wo);

    // ---- per-lane seq meta (lane&7 -> seq wseq+(lane&7)) ----
    int obase; float x0reg;
    {
        const int msl  = lane & 7;
        const int mseq = wseq + msl;
        const int mb   = mseq / CITY_;
        const int mc   = mseq - mb*CITY_;
        obase = mb*(PRED_*CITY_) + mc;
        x0reg = ldin<F32>(pm25, (long)(mb*HIST_ + (HIST_-1))*CITY_ + mc);
    }
    PIN(obase);

    // ---- feature staging: 8 seqs x 13 = 104 elems; lanes x 2 slots ----
    int fofs[2], fsl[2], fff[2];
    #pragma unroll
    for (int j = 0; j < 2; ++j) {
        int e = lane + 64*j;
        if (j == 1 && lane >= 40) e = lane;    // dummy, never stored
        const int sl = e / FEAT_;
        const int f  = e - sl*FEAT_;
        fsl[j] = sl; fff[j] = f;
        const int seq  = wseq + sl;
        const int b    = seq / CITY_;
        const int city = seq - b*CITY_;
        fofs[j] = ((b*(HIST_+PRED_) + HIST_)*CITY_ + city)*FEAT_ + f;
    }
    float fval[2];
    auto ldfeat = [&]() {
        #pragma unroll
        for (int j = 0; j < 2; ++j) {
            fval[j] = ldin<F32>(feat, (long)fofs[j]);
            fofs[j] += CITY_ * FEAT_;
        }
    };
    auto wrfeat = [&]() {
        fb[fsl[0]][fff[0]] = fval[0];
        if (lane < 40) fb[fsl[1]][fff[1]] = fval[1];
    };

    float cst[8];                    // c-state (valid on half0 lanes)

    auto round = [&](int t, int r, auto T0flag) {
        constexpr bool T0 = decltype(T0flag)::value;
        float acc0, acc1;
        if constexpr (T0) {
            const float x0 = __shfl(x0reg, r);          // readlane (const)
            acc0 = fmaf(a0r0, x0, bg0r0);
            acc1 = fmaf(a0r1, x0, bg0r1);
        } else {
            float a0a = bg2r0, a0b = 0.0f, a1a = bg2r1, a1b = 0.0f;
            const float* hp = &hb[r][0];                // broadcast reads
            #pragma unroll
            for (int k = 0; k < 16; ++k) {
                const float hA = hp[k], hB = hp[k+16];
                a0a = fmaf(Wh0[k],    hA, a0a);
                a1a = fmaf(Wh1[k],    hA, a1a);
                a0b = fmaf(Wh0[k+16], hB, a0b);
                a1b = fmaf(Wh1[k+16], hB, a1b);
            }
            acc0 = a0a + a0b; acc1 = a1a + a1b;
        }
        #pragma unroll
        for (int f = 0; f < 13; ++f) {
            const float fv = fb[r][f];
            acc0 = fmaf(Wf0[f], fv, acc0);
            acc1 = fmaf(Wf1[f], fv, acc1);
        }
        // half0 gate0 = sig(I); half1 gate0 = tanh(G) = 2*sig(2G)-1
        const float s0   = sigf(half ? 2.0f*acc0 : acc0);
        const float val0 = half ? fmaf(2.0f, s0, -1.0f) : s0;   // I / G
        const float g1   = sigf(acc1);                          // F / O
        const float xG   = __shfl_xor(val0, 32);   // half0 receives G
        const float prod = val0 * xG;              // half0: I*G
        const float cc   = T0 ? prod : fmaf(g1, cst[r], prod);
        cst[r] = cc;
        const float th = tanhf_(cc);
        const float xO = __shfl_xor(g1, 32);       // half0 receives O
        const float hu = xO * th;                  // half0: new h_u
        if (lane < 32) hb[r][u] = hu;
        float y = wo * hu;                         // reduce over half0
        y += __shfl_xor(y, 1);
        y += __shfl_xor(y, 2);
        y += __shfl_xor(y, 4);
        y += __shfl_xor(y, 8);
        y += __shfl_xor(y, 16);
        const int ob = __shfl(obase, r);           // readlane (const)
        if (lane == 0) stout<F32>(out, (long)(ob + t*CITY_), y + bo);
    };

    // ---- t = 0 ----
    ldfeat();            // t=0 features
    wrfeat();
    ldfeat();            // t=1 features in flight
    #pragma unroll
    for (int r = 0; r < 8; ++r) round(0, r, TrueT{});

    // ---- t = 1..23 ----
    #pragma unroll 1
    for (int t = 1; t < PRED_; ++t) {
        wrfeat();                       // features for t (loaded last iter)
        if (t < PRED_-1) ldfeat();      // prefetch t+1
        #pragma unroll
        for (int r = 0; r < 8; ++r) round(t, r, FalseT{});
    }
}

// 4 independent waves per block (beats the ~8 workgroups/CU slot cap seen
// at 21% occupancy in R3/R4 with 1-wave blocks). No __syncthreads.
__global__ __launch_bounds__(256) __attribute__((amdgpu_waves_per_eu(2, 3)))
void lstm_main(const void* __restrict__ pm25, const void* __restrict__ feat,
               const float* __restrict__ ws, void* __restrict__ out)
{
    __shared__ float hb[4][8][36];   // per-wave slices; stride 36 = 16B-aligned
    __shared__ float fb[4][8][16];
    const int wave = threadIdx.x >> 6;
    const int lane = threadIdx.x & 63;
    const int wseq = (blockIdx.x * 4 + wave) * 8;
    const bool f32 = (ws[FLAG_OFF] != 0.0f);
    if (f32) lstm_body<true >(pm25, feat, ws, out, hb[wave], fb[wave], lane, wseq);
    else     lstm_body<false>(pm25, feat, ws, out, hb[wave], fb[wave], lane, wseq);
}

extern "C" void kernel_launch(void* const* d_in, const int* in_sizes, int n_in,
                              void* d_out, int out_size, void* d_ws, size_t ws_size,
                              hipStream_t stream) {
    const void* pm25  = d_in[0];
    const void* feat  = d_in[1];
    float* ws = (float*)d_ws;

    prep_all<<<dim3(1), dim3(128), 0, stream>>>(
        (const unsigned short*)feat,
        d_in[2], d_in[3], d_in[4], d_in[5], d_in[6], d_in[7], d_in[8], d_in[9],
        ws);

    lstm_main<<<dim3(BC_/32), dim3(256), 0, stream>>>(pm25, feat, ws, d_out);
}

// Round 6
// 735.797 us; speedup vs baseline: 1.1325x; 1.0030x over previous
//
#include <hip/hip_runtime.h>
#include <hip/hip_bf16.h>

// Problem constants
#define B_    512
#define HIST_ 8
#define PRED_ 24
#define CITY_ 184
#define FEAT_ 13
#define HID_  32
#define BC_   (B_*CITY_)   // 94208 = 11776 waves * 8 seqs
#define FLAG_OFF 7168

// ws (float) layout (written by prep_all):
//   [0..4095]      Wh2[row*32+k] : W_hh + a0 (x) W_out   (t>=1 path)
//   [4096..6143]   Wf [row*16+f] : W_x[:,1:14], cols 13..15 zeroed
//   [6144..6271]   bg2[row]      : b_g + a0*b_out        (t>=1)
//   [6272..6399]   a0 [row]      : W_x[:,0]              (t==0)
//   [6400..6527]   bg0[row]      : b_g                   (t==0)
//   [6528..6559]   wout[k]
//   [6560]         bout
//   [7168]         dtype flag: 0.0f = bf16 inputs, 1.0f = fp32 inputs

// Anti-remat / anti-AGPR pin. Zero instructions — pure RA constraint.
// MUST be applied inside the loop body at each use region: a one-time pin
// lets the allocator live-range-split into AGPRs afterwards (R5 lesson).
#define PIN(x) asm volatile("" : "+v"(x))

struct TrueT  { static constexpr bool value = true;  };
struct FalseT { static constexpr bool value = false; };

__device__ __forceinline__ float rcp_(float x) { return __builtin_amdgcn_rcpf(x); }
__device__ __forceinline__ float sigf(float x) { return rcp_(1.0f + __expf(-x)); }
__device__ __forceinline__ float tanhf_(float x) {
    float e = __expf(2.0f * x);
    return 1.0f - 2.0f * rcp_(e + 1.0f);   // saturates correctly
}

template<bool F32>
__device__ __forceinline__ float ldin(const void* p, long i) {
    if constexpr (F32) return ((const float*)p)[i];
    else               return __bfloat162float(((const __hip_bfloat16*)p)[i]);
}
template<bool F32>
__device__ __forceinline__ void stout(void* p, long i, float v) {
    if constexpr (F32) ((float*)p)[i] = v;
    else               ((__hip_bfloat16*)p)[i] = __float2bfloat16(v);
}

// ---- weight folding (validated R2-R5) ----
template<bool F32>
__device__ __forceinline__ void prep_body(
    const void* __restrict__ W_in,  const void* __restrict__ b_in,
    const void* __restrict__ W_out, const void* __restrict__ b_out,
    const void* __restrict__ W_ih,  const void* __restrict__ W_hh,
    const void* __restrict__ b_ih,  const void* __restrict__ b_hh,
    float* __restrict__ ws, int j)
{
    float wx[14];
    #pragma unroll
    for (int c = 0; c < 14; ++c) wx[c] = 0.0f;
    float bg = ldin<F32>(b_ih, j) + ldin<F32>(b_hh, j);
    #pragma unroll
    for (int m = 0; m < 32; ++m) {
        float wihm = ldin<F32>(W_ih, j*32 + m);
        #pragma unroll
        for (int c = 0; c < 14; ++c) wx[c] = fmaf(wihm, ldin<F32>(W_in, m*14 + c), wx[c]);
        bg = fmaf(wihm, ldin<F32>(b_in, m), bg);
    }
    float a0 = wx[0];
    #pragma unroll
    for (int k = 0; k < 32; ++k)
        ws[j*32 + k] = ldin<F32>(W_hh, j*32 + k) + a0 * ldin<F32>(W_out, k);
    #pragma unroll
    for (int f = 0; f < 13; ++f) ws[4096 + j*16 + f] = wx[1 + f];
    #pragma unroll
    for (int f = 13; f < 16; ++f) ws[4096 + j*16 + f] = 0.0f;
    float bo = ldin<F32>(b_out, 0);
    ws[6144 + j] = bg + a0 * bo;
    ws[6272 + j] = a0;
    ws[6400 + j] = bg;
    if (j < 32) ws[6528 + j] = ldin<F32>(W_out, j);
    if (j == 0) ws[6560] = bo;
}

// Single dispatch: dtype detect (validated R2-R5) + fold, branch on result.
__global__ void prep_all(const unsigned short* __restrict__ feat_raw,
                         const void* __restrict__ W_in,  const void* __restrict__ b_in,
                         const void* __restrict__ W_out, const void* __restrict__ b_out,
                         const void* __restrict__ W_ih,  const void* __restrict__ W_hh,
                         const void* __restrict__ b_ih,  const void* __restrict__ b_hh,
                         float* __restrict__ ws)
{
    __shared__ int cnt;
    const int tid = threadIdx.x;     // 128 threads
    if (tid == 0) cnt = 0;
    __syncthreads();
    int insane = 0;
    for (int i = tid; i < 4096; i += 128) {
        float v = __uint_as_float(((unsigned int)feat_raw[i]) << 16);
        if (!(fabsf(v) < 1e8f)) insane++;   // catches NaN too
    }
    if (insane) atomicAdd(&cnt, insane);
    __syncthreads();
    const bool f32 = (cnt > 8);
    if (tid == 0) ws[FLAG_OFF] = f32 ? 1.0f : 0.0f;
    if (f32) prep_body<true >(W_in,b_in,W_out,b_out,W_ih,W_hh,b_ih,b_hh,ws,tid);
    else     prep_body<false>(W_in,b_in,W_out,b_out,W_ih,W_hh,b_ih,b_hh,ws,tid);
}

// Gate-split weight-stationary LSTM body. One wave, 8 sequences.
// half0 (lanes 0..31): gate rows u (i) and u+32 (f); half1: u+64 (g), u+96 (o).
template<bool F32>
__device__ __forceinline__ void lstm_body(
    const void* __restrict__ pm25, const void* __restrict__ feat,
    const float* __restrict__ ws, void* __restrict__ out,
    float (&hb)[8][36], float (&fb)[8][16], const int lane, const int wseq)
{
    const int u    = lane & 31;
    const int half = lane >> 5;
    const int row0 = u + 64*half;    // i / g
    const int row1 = row0 + 32;      // f / o

    // ---- resident weights ----
    float Wh0[32], Wh1[32], Wf0[13], Wf1[13];
    {
        const float* p0 = ws + row0*32;
        const float* p1 = ws + row1*32;
        #pragma unroll
        for (int k = 0; k < 32; ++k) { Wh0[k] = p0[k]; Wh1[k] = p1[k]; }
        const float* q0 = ws + 4096 + row0*16;
        const float* q1 = ws + 4096 + row1*16;
        #pragma unroll
        for (int f = 0; f < 13; ++f) { Wf0[f] = q0[f]; Wf1[f] = q1[f]; }
    }
    float bg2r0 = ws[6144 + row0], bg2r1 = ws[6144 + row1];
    float a0r0  = ws[6272 + row0], a0r1  = ws[6272 + row1];
    float bg0r0 = ws[6400 + row0], bg0r1 = ws[6400 + row1];
    float wo    = ws[6528 + u];
    const float bo = ws[6560];

    // ---- per-lane seq meta (lane&7 -> seq wseq+(lane&7)) ----
    int obase; float x0reg;
    {
        const int msl  = lane & 7;
        const int mseq = wseq + msl;
        const int mb   = mseq / CITY_;
        const int mc   = mseq - mb*CITY_;
        obase = mb*(PRED_*CITY_) + mc;
        x0reg = ldin<F32>(pm25, (long)(mb*HIST_ + (HIST_-1))*CITY_ + mc);
    }

    // ---- feature staging: 8 seqs x 13 = 104 elems; lanes x 2 slots ----
    int fofs[2], fsl[2], fff[2];
    #pragma unroll
    for (int j = 0; j < 2; ++j) {
        int e = lane + 64*j;
        if (j == 1 && lane >= 40) e = lane;    // dummy, never stored
        const int sl = e / FEAT_;
        const int f  = e - sl*FEAT_;
        fsl[j] = sl; fff[j] = f;
        const int seq  = wseq + sl;
        const int b    = seq / CITY_;
        const int city = seq - b*CITY_;
        fofs[j] = ((b*(HIST_+PRED_) + HIST_)*CITY_ + city)*FEAT_ + f;
    }
    float fval[2];
    auto ldfeat = [&]() {
        #pragma unroll
        for (int j = 0; j < 2; ++j) {
            fval[j] = ldin<F32>(feat, (long)fofs[j]);
            fofs[j] += CITY_ * FEAT_;
        }
    };
    auto wrfeat = [&]() {
        fb[fsl[0]][fff[0]] = fval[0];
        if (lane < 40) fb[fsl[1]][fff[1]] = fval[1];
    };

    float cst[8];                    // c-state (valid on half0 lanes)

    auto round = [&](int t, int r, auto T0flag) {
        constexpr bool T0 = decltype(T0flag)::value;

        // Re-pin ALL resident weights EVERY round (zero instructions).
        // AGPR live-range splitting would now need copies around every
        // use — never profitable — so weights stay in arch VGPRs.
        #pragma unroll
        for (int k = 0; k < 32; ++k) { PIN(Wh0[k]); PIN(Wh1[k]); }
        #pragma unroll
        for (int f = 0; f < 13; ++f) { PIN(Wf0[f]); PIN(Wf1[f]); }
        PIN(bg2r0); PIN(bg2r1); PIN(a0r0); PIN(a0r1);
        PIN(bg0r0); PIN(bg0r1); PIN(wo);

        float acc0, acc1;
        if constexpr (T0) {
            const float x0 = __shfl(x0reg, r);          // readlane (const)
            acc0 = fmaf(a0r0, x0, bg0r0);
            acc1 = fmaf(a0r1, x0, bg0r1);
        } else {
            float a0a = bg2r0, a0b = 0.0f, a1a = bg2r1, a1b = 0.0f;
            const float* hp = &hb[r][0];                // broadcast reads
            #pragma unroll
            for (int k = 0; k < 16; ++k) {
                const float hA = hp[k], hB = hp[k+16];
                a0a = fmaf(Wh0[k],    hA, a0a);
                a1a = fmaf(Wh1[k],    hA, a1a);
                a0b = fmaf(Wh0[k+16], hB, a0b);
                a1b = fmaf(Wh1[k+16], hB, a1b);
            }
            acc0 = a0a + a0b; acc1 = a1a + a1b;
        }
        #pragma unroll
        for (int f = 0; f < 13; ++f) {
            const float fv = fb[r][f];
            acc0 = fmaf(Wf0[f], fv, acc0);
            acc1 = fmaf(Wf1[f], fv, acc1);
        }
        // half0 gate0 = sig(I); half1 gate0 = tanh(G) = 2*sig(2G)-1
        const float s0   = sigf(half ? 2.0f*acc0 : acc0);
        const float val0 = half ? fmaf(2.0f, s0, -1.0f) : s0;   // I / G
        const float g1   = sigf(acc1);                          // F / O
        const float xG   = __shfl_xor(val0, 32);   // half0 receives G
        const float prod = val0 * xG;              // half0: I*G
        const float cc   = T0 ? prod : fmaf(g1, cst[r], prod);
        cst[r] = cc;
        const float th = tanhf_(cc);
        const float xO = __shfl_xor(g1, 32);       // half0 receives O
        const float hu = xO * th;                  // half0: new h_u
        if (lane < 32) hb[r][u] = hu;
        float y = wo * hu;                         // reduce over half0
        y += __shfl_xor(y, 1);
        y += __shfl_xor(y, 2);
        y += __shfl_xor(y, 4);
        y += __shfl_xor(y, 8);
        y += __shfl_xor(y, 16);
        const int ob = __shfl(obase, r);           // readlane (const)
        if (lane == 0) stout<F32>(out, (long)(ob + t*CITY_), y + bo);
    };

    // ---- t = 0 ----
    ldfeat();            // t=0 features
    wrfeat();
    ldfeat();            // t=1 features in flight
    #pragma unroll
    for (int r = 0; r < 8; ++r) round(0, r, TrueT{});

    // ---- t = 1..23 ----
    #pragma unroll 1
    for (int t = 1; t < PRED_; ++t) {
        wrfeat();                       // features for t (loaded last iter)
        if (t < PRED_-1) ldfeat();      // prefetch t+1
        #pragma unroll
        for (int r = 0; r < 8; ++r) round(t, r, FalseT{});
    }
}

// 4 independent waves per block (beats the ~8 workgroups/CU slot cap seen
// with 1-wave blocks in R3/R4). No __syncthreads.
__global__ __launch_bounds__(256) __attribute__((amdgpu_waves_per_eu(2, 4)))
void lstm_main(const void* __restrict__ pm25, const void* __restrict__ feat,
               const float* __restrict__ ws, void* __restrict__ out)
{
    __shared__ float hb[4][8][36];   // per-wave slices; stride 36 = 16B-aligned
    __shared__ float fb[4][8][16];
    const int wave = threadIdx.x >> 6;
    const int lane = threadIdx.x & 63;
    const int wseq = (blockIdx.x * 4 + wave) * 8;
    const bool f32 = (ws[FLAG_OFF] != 0.0f);
    if (f32) lstm_body<true >(pm25, feat, ws, out, hb[wave], fb[wave], lane, wseq);
    else     lstm_body<false>(pm25, feat, ws, out, hb[wave], fb[wave], lane, wseq);
}

extern "C" void kernel_launch(void* const* d_in, const int* in_sizes, int n_in,
                              void* d_out, int out_size, void* d_ws, size_t ws_size,
                              hipStream_t stream) {
    const void* pm25  = d_in[0];
    const void* feat  = d_in[1];
    float* ws = (float*)d_ws;

    prep_all<<<dim3(1), dim3(128), 0, stream>>>(
        (const unsigned short*)feat,
        d_in[2], d_in[3], d_in[4], d_in[5], d_in[6], d_in[7], d_in[8], d_in[9],
        ws);

    lstm_main<<<dim3(BC_/32), dim3(256), 0, stream>>>(pm25, feat, ws, d_out);
}